// Round 10
// baseline (533.514 us; speedup 1.0000x reference)
//
#include <hip/hip_runtime.h>
#include <hip/hip_fp16.h>

// RGCN 3-layer, transform-first with column-split passes:
//   Y = A @ [W_0..W_7, W_root] restricted to output cols [p*PW,(p+1)*PW)
//   h[n, cols] = relu( Y[n,rootblk] + sum_e (1/cnt[n,ty]) * Y[src_e, ty-blk] + bias )
// Edge sort: bucket pipeline (bucket = 256 dst nodes). sinvp precomputed.
// Edge pass: 16-lane subgroups, f16x4 vector gather, shfl sinv broadcast.
// GEMM: A-only LDS staging, OPERAND-SWAPPED MFMA (mfma(b,a)) so each lane owns
// 4 consecutive output cols -> direct f16x4 stores, no LDS repack epilogue.
// grid = (m-tiles, col-tiles): XCD re-reads its A panels from its own L2
// across column phases. Layer-2 pruned to marked nodes; layer 3 at roots only.

typedef _Float16 f16;
typedef _Float16 f16x2 __attribute__((ext_vector_type(2)));
typedef _Float16 f16x4 __attribute__((ext_vector_type(4)));
typedef _Float16 f16x8 __attribute__((ext_vector_type(8)));
typedef float f32x4 __attribute__((ext_vector_type(4)));

#define NREL 8
#define ACHUNK 8192

// ---------------- fallback setup kernels (N > 131072 only) ----------------
__global__ void k_hist(const int* __restrict__ dst, int E, int* __restrict__ cnt) {
  int e = blockIdx.x * 256 + threadIdx.x;
  if (e < E) atomicAdd(&cnt[dst[e]], 1);
}

__global__ void k_scan1(const int* __restrict__ in, int* __restrict__ out,
                        int* __restrict__ part, int n) {
  __shared__ int sh[256];
  int b = blockIdx.x, t = threadIdx.x;
  int base = b * 4096 + t * 16;
  int v[16]; int s = 0;
#pragma unroll
  for (int j = 0; j < 16; j++) { int idx = base + j; int x = (idx < n) ? in[idx] : 0; v[j] = s; s += x; }
  sh[t] = s; __syncthreads();
  for (int off = 1; off < 256; off <<= 1) {
    int x = 0; if (t >= off) x = sh[t - off];
    __syncthreads();
    if (t >= off) sh[t] += x;
    __syncthreads();
  }
  int excl = (t == 0) ? 0 : sh[t - 1];
  if (t == 255) part[b] = sh[255];
#pragma unroll
  for (int j = 0; j < 16; j++) { int idx = base + j; if (idx < n) out[idx] = v[j] + excl; }
}

__global__ void k_scan2(int* __restrict__ part, int nb) {
  __shared__ int sh[256];
  int t = threadIdx.x;
  sh[t] = (t < nb) ? part[t] : 0; __syncthreads();
  for (int off = 1; off < 256; off <<= 1) {
    int x = 0; if (t >= off) x = sh[t - off];
    __syncthreads();
    if (t >= off) sh[t] += x;
    __syncthreads();
  }
  if (t < nb) part[t] = (t == 0) ? 0 : sh[t - 1];
}

__global__ void k_scan3(int* __restrict__ out, const int* __restrict__ part, int n) {
  int i = blockIdx.x * 256 + threadIdx.x;
  if (i < n) out[i] += part[i >> 12];
}

__global__ void k_scatter(const int* __restrict__ src, const int* __restrict__ dstv,
                          const int* __restrict__ et, int E,
                          const int* __restrict__ off, int* __restrict__ fill,
                          int* __restrict__ sps) {
  int e = blockIdx.x * 256 + threadIdx.x;
  if (e >= E) return;
  int d = dstv[e];
  int pos = off[d] + atomicAdd(&fill[d], 1);
  sps[pos] = src[e] | (et[e] << 20);
}

__global__ void k_sentinel(int* __restrict__ p, int v) { *p = v; }

// ---------------- bucket pipeline (bucket = 256 consecutive dst nodes) ----------
__global__ __launch_bounds__(256) void k_bhist(const int* __restrict__ dstv, int E,
                                               int* __restrict__ bcnt, int nbuck) {
  __shared__ int h[512];
  int t = threadIdx.x;
  for (int i = t; i < 512; i += 256) h[i] = 0;
  __syncthreads();
  int lo = blockIdx.x * ACHUNK;
  int hi = lo + ACHUNK < E ? lo + ACHUNK : E;
  for (int e = lo + t; e < hi; e += 256) atomicAdd(&h[dstv[e] >> 8], 1);
  __syncthreads();
  for (int i = t; i < nbuck; i += 256)
    if (h[i]) atomicAdd(&bcnt[i], h[i]);
}

__global__ __launch_bounds__(512) void k_bscan(const int* __restrict__ bcnt,
                                               int* __restrict__ boff, int nbuck) {
  __shared__ int sh[512];
  int t = threadIdx.x;
  sh[t] = (t < nbuck) ? bcnt[t] : 0;
  __syncthreads();
  for (int o = 1; o < 512; o <<= 1) {
    int v = 0; if (t >= o) v = sh[t - o];
    __syncthreads();
    sh[t] += v;
    __syncthreads();
  }
  if (t <= nbuck && t < 512) boff[t] = (t == 0) ? 0 : sh[t - 1];
  if (t == 511 && nbuck >= 512) boff[nbuck] = sh[511];
}

__global__ __launch_bounds__(256) void k_bucketA(
    const int* __restrict__ src, const int* __restrict__ dstv,
    const int* __restrict__ et, int E, const int* __restrict__ boff,
    int* __restrict__ bfill, int* __restrict__ tmp, int nbuck) {
  __shared__ int hist[512];
  __shared__ int base[512];
  int t = threadIdx.x;
  int lo = blockIdx.x * ACHUNK;
  int hi = lo + ACHUNK < E ? lo + ACHUNK : E;
  for (int i = t; i < nbuck; i += 256) hist[i] = 0;
  __syncthreads();
  for (int e = lo + t; e < hi; e += 256)
    atomicAdd(&hist[dstv[e] >> 8], 1);
  __syncthreads();
  for (int i = t; i < nbuck; i += 256) {
    int c = hist[i];
    base[i] = c ? (boff[i] + atomicAdd(&bfill[i], c)) : 0;
  }
  __syncthreads();
  for (int e = lo + t; e < hi; e += 256) {
    int d = dstv[e];
    int b = d >> 8;
    int pos = atomicAdd(&base[b], 1);
    tmp[pos] = src[e] | (et[e] << 20) | ((d & 255) << 23);
  }
}

__global__ __launch_bounds__(256) void k_bucketB2(const int* __restrict__ tmp,
                                                  const int* __restrict__ boff,
                                                  int* __restrict__ off,
                                                  int* __restrict__ sps, int N) {
  __shared__ int cnt[256];
  __shared__ int sh[256];
  __shared__ int loff[257];
  int b = blockIdx.x, t = threadIdx.x;
  int n0 = b << 8;
  int nn = (N - n0) < 256 ? (N - n0) : 256;
  cnt[t] = 0;
  __syncthreads();
  int e0 = boff[b], e1 = boff[b + 1];
  for (int e = e0 + t; e < e1; e += 256)
    atomicAdd(&cnt[(tmp[e] >> 23) & 255], 1);
  __syncthreads();
  sh[t] = cnt[t];
  __syncthreads();
  for (int o = 1; o < 256; o <<= 1) {
    int v = 0; if (t >= o) v = sh[t - o];
    __syncthreads();
    sh[t] += v;
    __syncthreads();
  }
  loff[t] = (t == 0) ? 0 : sh[t - 1];
  if (t == 255) loff[256] = sh[255];
  __syncthreads();
  if (t < nn) off[n0 + t] = e0 + loff[t];
  cnt[t] = 0;   // reuse as fill
  __syncthreads();
  for (int e = e0 + t; e < e1; e += 256) {
    int v = tmp[e];
    int dl = (v >> 23) & 255;
    int pos = e0 + loff[dl] + atomicAdd(&cnt[dl], 1);
    sps[pos] = v & 0x7FFFFF;
  }
}

// mark nodes whose h2 is read by layer 3: roots + src of root in-edges
__global__ void k_mark(const int* __restrict__ ridx, const int* __restrict__ off,
                       const int* __restrict__ sps, int* __restrict__ mark) {
  int i = blockIdx.x, t = threadIdx.x;
  int n = ridx[i];
  if (t == 0) mark[n] = 1;
  int e0 = off[n], e1 = off[n + 1];
  for (int e = e0 + t; e < e1; e += 64) mark[sps[e] & 0xFFFFF] = 1;
}

// precompute per-(node,type) inverse counts
__global__ __launch_bounds__(256) void k_sinvp(const int* __restrict__ sps,
                                               const int* __restrict__ off,
                                               float* __restrict__ sinvp, int N) {
  __shared__ int c[16][8];
  int t = threadIdx.x;
  int g = t >> 4, st = t & 15;
  int n = blockIdx.x * 16 + g;
  if (st < 8) c[g][st] = 0;
  __syncthreads();
  if (n < N) {
    int e0 = off[n], e1 = off[n + 1];
    for (int e = e0 + st; e < e1; e += 16)
      atomicAdd(&c[g][((unsigned)sps[e]) >> 20], 1);
  }
  __syncthreads();
  if (n < N && st < 8) {
    int cc = c[g][st];
    sinvp[n * 8 + st] = 1.0f / (float)(cc > 1 ? cc : 1);
  }
}

__global__ void k_f32_to_f16(const float* __restrict__ in, f16* __restrict__ out, int n4) {
  int i = blockIdx.x * 256 + threadIdx.x;
  if (i < n4) {
    float4 v = ((const float4*)in)[i];
    f16x4 o; o[0] = (f16)v.x; o[1] = (f16)v.y; o[2] = (f16)v.z; o[3] = (f16)v.w;
    ((f16x4*)out)[i] = o;
  }
}

// weights for pass p: Wt[row][k], row = cb*PW + j -> source col p*PW+j of chunk cb
__global__ void k_tpw(const float* __restrict__ wrel, const float* __restrict__ wroot,
                      f16* __restrict__ dst, int PW, int p) {
  int row = blockIdx.x, k = threadIdx.x;
  float v = 0.f;
  if (row < 9 * PW) {
    int cb = row / PW, j = row - cb * PW;
    int col = p * PW + j;
    v = (cb < 8) ? wrel[(size_t)cb * 16384 + k * 128 + col] : wroot[k * 128 + col];
  }
  dst[(size_t)row * 128 + k] = (f16)v;
}

// ---------------- GEMM: C[M x ncol] = A[M x 128] * Bt^T ----------------
// Operand-swapped MFMA: mfma(b, a) -> lane owns row m = lm, 4 consecutive cols
// n = lk*4+q per (i,j) fragment -> direct f16x4 stores, no epilogue repack.
__global__ __launch_bounds__(256, 4) void k_gemm2(const f16* __restrict__ A,
                                                  const f16* __restrict__ Bt,
                                                  f16* __restrict__ C, int M, int ncol) {
  __shared__ f16 As[128 * 136];
  int tid = threadIdx.x;
  int m0 = blockIdx.x * 128, n0 = blockIdx.y * 128;
#pragma unroll
  for (int cch = 0; cch < 8; cch++) {
    int ci = tid + cch * 256;
    int row = ci >> 4, c8 = ci & 15;
    int gm = m0 + row;
    f16x8 va = {};
    if (gm < M) va = *(const f16x8*)(A + (size_t)gm * 128 + c8 * 8);
    *(f16x8*)(As + row * 136 + c8 * 8) = va;
  }
  __syncthreads();
  int wid = tid >> 6, lane = tid & 63;
  int wm = (wid & 1) * 64, wn = (wid >> 1) * 64;
  int lm = lane & 15, lk = lane >> 4;
  f32x4 acc[4][4] = {};
#pragma unroll
  for (int ks = 0; ks < 4; ks++) {
    int k0 = ks * 32;
    f16x8 a[4], b[4];
#pragma unroll
    for (int j = 0; j < 4; j++)
      b[j] = *(const f16x8*)(Bt + (size_t)(n0 + wn + j * 16 + lm) * 128 + k0 + lk * 8);
#pragma unroll
    for (int i = 0; i < 4; i++)
      a[i] = *(const f16x8*)(As + (wm + i * 16 + lm) * 136 + k0 + lk * 8);
#pragma unroll
    for (int i = 0; i < 4; i++)
#pragma unroll
      for (int j = 0; j < 4; j++)
        acc[i][j] = __builtin_amdgcn_mfma_f32_16x16x32_f16(b[j], a[i], acc[i][j], 0, 0, 0);
  }
  // direct stores: row gm = m0+wm+i*16+lm, cols gn..gn+3 = n0+wn+j*16+lk*4
#pragma unroll
  for (int i = 0; i < 4; i++) {
    int gm = m0 + wm + i * 16 + lm;
    if (gm >= M) continue;
#pragma unroll
    for (int j = 0; j < 4; j++) {
      int gn = n0 + wn + j * 16 + lk * 4;
      if (gn < ncol) {
        f16x4 o;
        o[0] = (f16)acc[i][j][0]; o[1] = (f16)acc[i][j][1];
        o[2] = (f16)acc[i][j][2]; o[3] = (f16)acc[i][j][3];
        *(f16x4*)(C + (size_t)gm * ncol + gn) = o;
      }
    }
  }
}

// ---------------- vectorized edge aggregation for one column pass ----------------
template <int PW>
__global__ __launch_bounds__(256) void k_edge_v(
    const f16* __restrict__ Y, const int* __restrict__ sps,
    const int* __restrict__ off, const float* __restrict__ sinvp,
    const float* __restrict__ bias, f16* __restrict__ hout,
    const int* __restrict__ mark, int N, int pass) {
  constexpr int CPL = PW / 16;
  constexpr int LDY = 9 * PW;
  int t = threadIdx.x;
  int g = t >> 4, st = t & 15;
  int n = blockIdx.x * 16 + g;
  if (n >= N) return;
  if (mark && !mark[n]) return;
  float sv = (st < 8) ? sinvp[n * 8 + st] : 0.f;
  int e0 = off[n], e1 = off[n + 1];
  float a[CPL], b2[CPL];
  {
    const f16* rp = Y + (size_t)n * LDY + 8 * PW + st * CPL;
    const float* bp = bias + pass * PW + st * CPL;
#pragma unroll
    for (int q = 0; q < CPL; q++) { a[q] = (float)rp[q] + bp[q]; b2[q] = 0.f; }
  }
  int sgbase = t & 48;
  int e = e0;
  for (; e + 1 < e1; e += 2) {
    int p0 = sps[e], p1 = sps[e + 1];
    int s0 = p0 & 0xFFFFF, ty0 = ((unsigned)p0) >> 20;
    int s1 = p1 & 0xFFFFF, ty1 = ((unsigned)p1) >> 20;
    float sc0 = __shfl(sv, sgbase | ty0);
    float sc1 = __shfl(sv, sgbase | ty1);
    const f16* q0 = Y + (size_t)s0 * LDY + ty0 * PW + st * CPL;
    const f16* q1 = Y + (size_t)s1 * LDY + ty1 * PW + st * CPL;
    if constexpr (PW == 64) {
      f16x4 v0 = *(const f16x4*)q0;
      f16x4 v1 = *(const f16x4*)q1;
      a[0] += (float)v0[0] * sc0; a[1] += (float)v0[1] * sc0;
      a[2] += (float)v0[2] * sc0; a[3] += (float)v0[3] * sc0;
      b2[0] += (float)v1[0] * sc1; b2[1] += (float)v1[1] * sc1;
      b2[2] += (float)v1[2] * sc1; b2[3] += (float)v1[3] * sc1;
    } else {
      f16x2 v0 = *(const f16x2*)q0;
      f16x2 v1 = *(const f16x2*)q1;
      a[0] += (float)v0[0] * sc0; a[1] += (float)v0[1] * sc0;
      b2[0] += (float)v1[0] * sc1; b2[1] += (float)v1[1] * sc1;
    }
  }
  if (e < e1) {
    int p0 = sps[e];
    int s0 = p0 & 0xFFFFF, ty0 = ((unsigned)p0) >> 20;
    float sc0 = __shfl(sv, sgbase | ty0);
    const f16* q0 = Y + (size_t)s0 * LDY + ty0 * PW + st * CPL;
    if constexpr (PW == 64) {
      f16x4 v0 = *(const f16x4*)q0;
      a[0] += (float)v0[0] * sc0; a[1] += (float)v0[1] * sc0;
      a[2] += (float)v0[2] * sc0; a[3] += (float)v0[3] * sc0;
    } else {
      f16x2 v0 = *(const f16x2*)q0;
      a[0] += (float)v0[0] * sc0; a[1] += (float)v0[1] * sc0;
    }
  }
  if constexpr (PW == 64) {
    f16x4 o;
#pragma unroll
    for (int q = 0; q < 4; q++) o[q] = (f16)fmaxf(a[q] + b2[q], 0.f);
    *(f16x4*)(hout + (size_t)n * 128 + pass * PW + st * 4) = o;
  } else {
    f16x2 o;
#pragma unroll
    for (int q = 0; q < 2; q++) o[q] = (f16)fmaxf(a[q] + b2[q], 0.f);
    *(f16x2*)(hout + (size_t)n * 128 + pass * PW + st * 2) = o;
  }
}

// ---------------- layer 3: only at root rows, weights in LDS ----------------
__global__ __launch_bounds__(128) void k_layer3(const f16* __restrict__ h2,
                                                const int* __restrict__ sps,
                                                const int* __restrict__ off,
                                                const float* __restrict__ sinvp,
                                                const int* __restrict__ ridx,
                                                const float* __restrict__ wrel,
                                                const float* __restrict__ wroot,
                                                const float* __restrict__ b3,
                                                float* __restrict__ out) {
  __shared__ f16 W[9 * 2048];
  __shared__ float red[2][16];
  __shared__ float sinv_s[8];
  int t = threadIdx.x;
  int n = ridx[blockIdx.x];
  for (int j = t; j < 9 * 2048; j += 128)
    W[j] = (f16)((j < 8 * 2048) ? wrel[j] : wroot[j - 8 * 2048]);
  if (t < 8) sinv_s[t] = sinvp[n * 8 + t];
  __syncthreads();
  int e0 = off[n], e1 = off[n + 1];
  int c = t & 15, kg = t >> 4;
  float a = 0.f;
  for (int e = e0; e < e1; e++) {
    int ps = sps[e];
    int s = ps & 0xFFFFF, ty = ((unsigned)ps) >> 20;
    float p = 0.f;
#pragma unroll
    for (int j = 0; j < 16; j++) {
      int k = kg * 16 + j;
      p += (float)h2[(size_t)s * 128 + k] * (float)W[ty * 2048 + k * 16 + c];
    }
    a += sinv_s[ty] * p;
  }
  {
    float p = 0.f;
#pragma unroll
    for (int j = 0; j < 16; j++) {
      int k = kg * 16 + j;
      p += (float)h2[(size_t)n * 128 + k] * (float)W[8 * 2048 + k * 16 + c];
    }
    a += p;
  }
  a += __shfl_xor(a, 16);
  a += __shfl_xor(a, 32);
  if ((t & 63) < 16) red[t >> 6][t & 15] = a;
  __syncthreads();
  if (t < 16) out[(size_t)blockIdx.x * 16 + t] = red[0][t] + red[1][t] + b3[t];
}

// ---------------- host ----------------
extern "C" void kernel_launch(void* const* d_in, const int* in_sizes, int n_in,
                              void* d_out, int out_size, void* d_ws, size_t ws_size,
                              hipStream_t stream) {
  const float* x     = (const float*)d_in[0];
  const int*   eidx  = (const int*)d_in[1];
  const int*   etyp  = (const int*)d_in[2];
  const int*   ridx  = (const int*)d_in[3];
  const float* wrel1 = (const float*)d_in[4];
  const float* root1 = (const float*)d_in[5];
  const float* b1    = (const float*)d_in[6];
  const float* wrel2 = (const float*)d_in[7];
  const float* root2 = (const float*)d_in[8];
  const float* b2    = (const float*)d_in[9];
  const float* wrel3 = (const float*)d_in[10];
  const float* root3 = (const float*)d_in[11];
  const float* b3    = (const float*)d_in[12];

  int N = in_sizes[0] / 128;
  int E = in_sizes[2];
  int NROOT = in_sizes[3];
  const int* esrc = eidx;
  const int* edst = eidx + E;

  char* p = (char*)d_ws;
  auto alloc = [&](size_t bytes) { void* r = (void*)p; p += (bytes + 255) & ~(size_t)255; return r; };
  int*   off   = (int*)alloc((size_t)(N + 1) * 4);
  int*   sps   = (int*)alloc((size_t)E * 4);
  f16*   h1    = (f16*)alloc((size_t)N * 128 * 2);
  f16*   h2    = (f16*)alloc((size_t)N * 128 * 2);   // also holds f16(x) for layer 1
  int*   mark  = (int*)alloc((size_t)N * 4);
  float* sinvp = (float*)alloc((size_t)N * 8 * 4);
  f16*   Wt    = (f16*)alloc((size_t)640 * 128 * 2);
  int*   bcnt  = (int*)alloc(512 * 4);
  int*   boff  = (int*)alloc(513 * 4);
  int*   bfill = (int*)alloc(512 * 4);

  size_t used = (size_t)(p - (char*)d_ws);
  size_t remain = ws_size > used ? ws_size - used : 0;
  int PW = (remain >= (size_t)N * 9 * 64 * 2 + (1u << 20)) ? 64 : 32;
  int ldy = 9 * PW;
  f16* Y = (f16*)alloc((size_t)N * ldy * 2);
  // setup-only scratch lives in Y's region (dead until first GEMM writes Y):
  int* tmp  = (int*)Y;             // E ints (phase-A bucket-grouped edges)
  int* part = tmp + E;             // 4096 ints (fallback scan partials)
  int* fill = part + 4096;         // N ints (fallback scatter only)

  int nbuck = (N + 255) >> 8;
  int nbA = (E + ACHUNK - 1) / ACHUNK;
  hipMemsetAsync(mark, 0, (size_t)N * 4, stream);

  if (nbuck <= 512) {
    hipMemsetAsync(bcnt, 0, 512 * 4, stream);
    hipMemsetAsync(bfill, 0, 512 * 4, stream);
    k_bhist<<<nbA, 256, 0, stream>>>(edst, E, bcnt, nbuck);
    k_bscan<<<1, 512, 0, stream>>>(bcnt, boff, nbuck);
    k_bucketA<<<nbA, 256, 0, stream>>>(esrc, edst, etyp, E, boff, bfill, tmp, nbuck);
    k_bucketB2<<<nbuck, 256, 0, stream>>>(tmp, boff, off, sps, N);
    k_sentinel<<<1, 1, 0, stream>>>(off + N, E);
  } else {
    int eb = (E + 255) / 256;
    hipMemsetAsync(off, 0, (size_t)(N + 1) * 4, stream);
    hipMemsetAsync(fill, 0, (size_t)N * 4, stream);
    k_hist<<<eb, 256, 0, stream>>>(edst, E, off);
    int nb1 = (N + 4095) / 4096;
    k_scan1<<<nb1, 256, 0, stream>>>(off, off, part, N);
    k_scan2<<<1, 256, 0, stream>>>(part, nb1);
    k_scan3<<<(N + 255) / 256, 256, 0, stream>>>(off, part, N);
    k_sentinel<<<1, 1, 0, stream>>>(off + N, E);
    k_scatter<<<eb, 256, 0, stream>>>(esrc, edst, etyp, E, off, fill, sps);
  }
  k_mark<<<NROOT, 64, 0, stream>>>(ridx, off, sps, mark);
  int ng16 = (N + 15) / 16;
  k_sinvp<<<ng16, 256, 0, stream>>>(sps, off, sinvp, N);
  k_f32_to_f16<<<((N * 32) + 255) / 256, 256, 0, stream>>>(x, h2, N * 32);

  int mb = (N + 127) / 128;
  int NT = (ldy + 127) / 128;
  int npass = 128 / PW;

  // layer 1: A = f16(x) (aliased in h2)
  for (int ps = 0; ps < npass; ps++) {
    k_tpw<<<NT * 128, 128, 0, stream>>>(wrel1, root1, Wt, PW, ps);
    k_gemm2<<<dim3(mb, NT), 256, 0, stream>>>(h2, Wt, Y, N, ldy);
    if (PW == 64)
      k_edge_v<64><<<ng16, 256, 0, stream>>>(Y, sps, off, sinvp, b1, h1, nullptr, N, ps);
    else
      k_edge_v<32><<<ng16, 256, 0, stream>>>(Y, sps, off, sinvp, b1, h1, nullptr, N, ps);
  }
  // layer 2: A = h1, edge pass pruned to marked nodes
  for (int ps = 0; ps < npass; ps++) {
    k_tpw<<<NT * 128, 128, 0, stream>>>(wrel2, root2, Wt, PW, ps);
    k_gemm2<<<dim3(mb, NT), 256, 0, stream>>>(h1, Wt, Y, N, ldy);
    if (PW == 64)
      k_edge_v<64><<<ng16, 256, 0, stream>>>(Y, sps, off, sinvp, b2, h2, mark, N, ps);
    else
      k_edge_v<32><<<ng16, 256, 0, stream>>>(Y, sps, off, sinvp, b2, h2, mark, N, ps);
  }
  k_layer3<<<NROOT, 128, 0, stream>>>(h2, sps, off, sinvp, ridx, wrel3, root3, b3,
                                      (float*)d_out);
}

// Round 11
// 494.419 us; speedup vs baseline: 1.0791x; 1.0791x over previous
//
#include <hip/hip_runtime.h>
#include <hip/hip_fp16.h>

// RGCN 3-layer, transform-first with column-split passes:
//   Y = A @ [W_0..W_7, W_root] restricted to output cols [p*PW,(p+1)*PW)
//   h[n, cols] = relu( Y[n,rootblk] + sum_e (1/cnt[n,ty]) * Y[src_e, ty-blk] + bias )
// Edge sort: bucket pipeline (bucket = 256 dst nodes). sinvp precomputed.
// Edge pass: 16-lane subgroups, f16x4 vector gather, shfl sinv broadcast.
// GEMM (k_gemm3): one block per 128-row m-tile; A staged once -> registers;
// internal loop over col-tiles; swapped MFMA (mfma(b,a)) -> f16x4 LDS repack
// (As reused as H) -> coalesced f16x8 global stores.
// Layer-2 pruned to marked nodes; layer 3 at roots only.

typedef _Float16 f16;
typedef _Float16 f16x2 __attribute__((ext_vector_type(2)));
typedef _Float16 f16x4 __attribute__((ext_vector_type(4)));
typedef _Float16 f16x8 __attribute__((ext_vector_type(8)));
typedef float f32x4 __attribute__((ext_vector_type(4)));

#define NREL 8
#define ACHUNK 8192

// ---------------- fallback setup kernels (N > 131072 only) ----------------
__global__ void k_hist(const int* __restrict__ dst, int E, int* __restrict__ cnt) {
  int e = blockIdx.x * 256 + threadIdx.x;
  if (e < E) atomicAdd(&cnt[dst[e]], 1);
}

__global__ void k_scan1(const int* __restrict__ in, int* __restrict__ out,
                        int* __restrict__ part, int n) {
  __shared__ int sh[256];
  int b = blockIdx.x, t = threadIdx.x;
  int base = b * 4096 + t * 16;
  int v[16]; int s = 0;
#pragma unroll
  for (int j = 0; j < 16; j++) { int idx = base + j; int x = (idx < n) ? in[idx] : 0; v[j] = s; s += x; }
  sh[t] = s; __syncthreads();
  for (int off = 1; off < 256; off <<= 1) {
    int x = 0; if (t >= off) x = sh[t - off];
    __syncthreads();
    if (t >= off) sh[t] += x;
    __syncthreads();
  }
  int excl = (t == 0) ? 0 : sh[t - 1];
  if (t == 255) part[b] = sh[255];
#pragma unroll
  for (int j = 0; j < 16; j++) { int idx = base + j; if (idx < n) out[idx] = v[j] + excl; }
}

__global__ void k_scan2(int* __restrict__ part, int nb) {
  __shared__ int sh[256];
  int t = threadIdx.x;
  sh[t] = (t < nb) ? part[t] : 0; __syncthreads();
  for (int off = 1; off < 256; off <<= 1) {
    int x = 0; if (t >= off) x = sh[t - off];
    __syncthreads();
    if (t >= off) sh[t] += x;
    __syncthreads();
  }
  if (t < nb) part[t] = (t == 0) ? 0 : sh[t - 1];
}

__global__ void k_scan3(int* __restrict__ out, const int* __restrict__ part, int n) {
  int i = blockIdx.x * 256 + threadIdx.x;
  if (i < n) out[i] += part[i >> 12];
}

__global__ void k_scatter(const int* __restrict__ src, const int* __restrict__ dstv,
                          const int* __restrict__ et, int E,
                          const int* __restrict__ off, int* __restrict__ fill,
                          int* __restrict__ sps) {
  int e = blockIdx.x * 256 + threadIdx.x;
  if (e >= E) return;
  int d = dstv[e];
  int pos = off[d] + atomicAdd(&fill[d], 1);
  sps[pos] = src[e] | (et[e] << 20);
}

__global__ void k_sentinel(int* __restrict__ p, int v) { *p = v; }

// ---------------- bucket pipeline (bucket = 256 consecutive dst nodes) ----------
__global__ __launch_bounds__(256) void k_bhist(const int* __restrict__ dstv, int E,
                                               int* __restrict__ bcnt, int nbuck) {
  __shared__ int h[512];
  int t = threadIdx.x;
  for (int i = t; i < 512; i += 256) h[i] = 0;
  __syncthreads();
  int lo = blockIdx.x * ACHUNK;
  int hi = lo + ACHUNK < E ? lo + ACHUNK : E;
  for (int e = lo + t; e < hi; e += 256) atomicAdd(&h[dstv[e] >> 8], 1);
  __syncthreads();
  for (int i = t; i < nbuck; i += 256)
    if (h[i]) atomicAdd(&bcnt[i], h[i]);
}

__global__ __launch_bounds__(512) void k_bscan(const int* __restrict__ bcnt,
                                               int* __restrict__ boff, int nbuck) {
  __shared__ int sh[512];
  int t = threadIdx.x;
  sh[t] = (t < nbuck) ? bcnt[t] : 0;
  __syncthreads();
  for (int o = 1; o < 512; o <<= 1) {
    int v = 0; if (t >= o) v = sh[t - o];
    __syncthreads();
    sh[t] += v;
    __syncthreads();
  }
  if (t <= nbuck && t < 512) boff[t] = (t == 0) ? 0 : sh[t - 1];
  if (t == 511 && nbuck >= 512) boff[nbuck] = sh[511];
}

__global__ __launch_bounds__(256) void k_bucketA(
    const int* __restrict__ src, const int* __restrict__ dstv,
    const int* __restrict__ et, int E, const int* __restrict__ boff,
    int* __restrict__ bfill, int* __restrict__ tmp, int nbuck) {
  __shared__ int hist[512];
  __shared__ int base[512];
  int t = threadIdx.x;
  int lo = blockIdx.x * ACHUNK;
  int hi = lo + ACHUNK < E ? lo + ACHUNK : E;
  for (int i = t; i < nbuck; i += 256) hist[i] = 0;
  __syncthreads();
  for (int e = lo + t; e < hi; e += 256)
    atomicAdd(&hist[dstv[e] >> 8], 1);
  __syncthreads();
  for (int i = t; i < nbuck; i += 256) {
    int c = hist[i];
    base[i] = c ? (boff[i] + atomicAdd(&bfill[i], c)) : 0;
  }
  __syncthreads();
  for (int e = lo + t; e < hi; e += 256) {
    int d = dstv[e];
    int b = d >> 8;
    int pos = atomicAdd(&base[b], 1);
    tmp[pos] = src[e] | (et[e] << 20) | ((d & 255) << 23);
  }
}

__global__ __launch_bounds__(256) void k_bucketB2(const int* __restrict__ tmp,
                                                  const int* __restrict__ boff,
                                                  int* __restrict__ off,
                                                  int* __restrict__ sps, int N) {
  __shared__ int cnt[256];
  __shared__ int sh[256];
  __shared__ int loff[257];
  int b = blockIdx.x, t = threadIdx.x;
  int n0 = b << 8;
  int nn = (N - n0) < 256 ? (N - n0) : 256;
  cnt[t] = 0;
  __syncthreads();
  int e0 = boff[b], e1 = boff[b + 1];
  for (int e = e0 + t; e < e1; e += 256)
    atomicAdd(&cnt[(tmp[e] >> 23) & 255], 1);
  __syncthreads();
  sh[t] = cnt[t];
  __syncthreads();
  for (int o = 1; o < 256; o <<= 1) {
    int v = 0; if (t >= o) v = sh[t - o];
    __syncthreads();
    sh[t] += v;
    __syncthreads();
  }
  loff[t] = (t == 0) ? 0 : sh[t - 1];
  if (t == 255) loff[256] = sh[255];
  __syncthreads();
  if (t < nn) off[n0 + t] = e0 + loff[t];
  cnt[t] = 0;   // reuse as fill
  __syncthreads();
  for (int e = e0 + t; e < e1; e += 256) {
    int v = tmp[e];
    int dl = (v >> 23) & 255;
    int pos = e0 + loff[dl] + atomicAdd(&cnt[dl], 1);
    sps[pos] = v & 0x7FFFFF;
  }
}

// mark nodes whose h2 is read by layer 3: roots + src of root in-edges
__global__ void k_mark(const int* __restrict__ ridx, const int* __restrict__ off,
                       const int* __restrict__ sps, int* __restrict__ mark) {
  int i = blockIdx.x, t = threadIdx.x;
  int n = ridx[i];
  if (t == 0) mark[n] = 1;
  int e0 = off[n], e1 = off[n + 1];
  for (int e = e0 + t; e < e1; e += 64) mark[sps[e] & 0xFFFFF] = 1;
}

// precompute per-(node,type) inverse counts
__global__ __launch_bounds__(256) void k_sinvp(const int* __restrict__ sps,
                                               const int* __restrict__ off,
                                               float* __restrict__ sinvp, int N) {
  __shared__ int c[16][8];
  int t = threadIdx.x;
  int g = t >> 4, st = t & 15;
  int n = blockIdx.x * 16 + g;
  if (st < 8) c[g][st] = 0;
  __syncthreads();
  if (n < N) {
    int e0 = off[n], e1 = off[n + 1];
    for (int e = e0 + st; e < e1; e += 16)
      atomicAdd(&c[g][((unsigned)sps[e]) >> 20], 1);
  }
  __syncthreads();
  if (n < N && st < 8) {
    int cc = c[g][st];
    sinvp[n * 8 + st] = 1.0f / (float)(cc > 1 ? cc : 1);
  }
}

__global__ void k_f32_to_f16(const float* __restrict__ in, f16* __restrict__ out, int n4) {
  int i = blockIdx.x * 256 + threadIdx.x;
  if (i < n4) {
    float4 v = ((const float4*)in)[i];
    f16x4 o; o[0] = (f16)v.x; o[1] = (f16)v.y; o[2] = (f16)v.z; o[3] = (f16)v.w;
    ((f16x4*)out)[i] = o;
  }
}

// weights for pass p: Wt[row][k], row = cb*PW + j -> source col p*PW+j of chunk cb
__global__ void k_tpw(const float* __restrict__ wrel, const float* __restrict__ wroot,
                      f16* __restrict__ dst, int PW, int p) {
  int row = blockIdx.x, k = threadIdx.x;
  float v = 0.f;
  if (row < 9 * PW) {
    int cb = row / PW, j = row - cb * PW;
    int col = p * PW + j;
    v = (cb < 8) ? wrel[(size_t)cb * 16384 + k * 128 + col] : wroot[k * 128 + col];
  }
  dst[(size_t)row * 128 + k] = (f16)v;
}

// ---------------- GEMM: C[M x ncol] = A[M x 128] * Bt^T ----------------
// One block per 128-row m-tile. A staged once -> 16 reg fragments; As reused
// as repack buffer H. Internal loop over (ncol+127)/128 col-tiles. Swapped
// MFMA: lane owns (row=lm, 4 consecutive cols) -> f16x4 LDS repack ->
// coalesced f16x8 global stores.
__global__ __launch_bounds__(256) void k_gemm3(const f16* __restrict__ A,
                                               const f16* __restrict__ Bt,
                                               f16* __restrict__ C, int M, int ncol) {
  __shared__ f16 As[128 * 136];
  int tid = threadIdx.x;
  int m0 = blockIdx.x * 128;
#pragma unroll
  for (int cch = 0; cch < 8; cch++) {
    int ci = tid + cch * 256;
    int row = ci >> 4, c8 = ci & 15;
    int gm = m0 + row;
    f16x8 va = {};
    if (gm < M) va = *(const f16x8*)(A + (size_t)gm * 128 + c8 * 8);
    *(f16x8*)(As + row * 136 + c8 * 8) = va;
  }
  __syncthreads();
  int wid = tid >> 6, lane = tid & 63;
  int wm = (wid & 1) * 64, wn = (wid >> 1) * 64;
  int lm = lane & 15, lk = lane >> 4;
  // A fragments to registers (4 ks x 4 i); As is then dead -> reuse as H
  f16x8 af[4][4];
#pragma unroll
  for (int ks = 0; ks < 4; ks++)
#pragma unroll
    for (int i = 0; i < 4; i++)
      af[ks][i] = *(const f16x8*)(As + (wm + i * 16 + lm) * 136 + ks * 32 + lk * 8);
  __syncthreads();
  f16* H = As;
  int NT = (ncol + 127) >> 7;
  for (int nt = 0; nt < NT; nt++) {
    int n0 = nt * 128;
    f32x4 acc[4][4] = {};
#pragma unroll
    for (int ks = 0; ks < 4; ks++) {
      f16x8 b[4];
#pragma unroll
      for (int j = 0; j < 4; j++)
        b[j] = *(const f16x8*)(Bt + (size_t)(n0 + wn + j * 16 + lm) * 128 + ks * 32 + lk * 8);
#pragma unroll
      for (int i = 0; i < 4; i++)
#pragma unroll
        for (int j = 0; j < 4; j++)
          acc[i][j] = __builtin_amdgcn_mfma_f32_16x16x32_f16(b[j], af[ks][i], acc[i][j], 0, 0, 0);
    }
    // repack: lane owns row (wm+i*16+lm), cols (wn+j*16+lk*4 .. +3)
#pragma unroll
    for (int i = 0; i < 4; i++)
#pragma unroll
      for (int j = 0; j < 4; j++) {
        f16x4 o;
        o[0] = (f16)acc[i][j][0]; o[1] = (f16)acc[i][j][1];
        o[2] = (f16)acc[i][j][2]; o[3] = (f16)acc[i][j][3];
        *(f16x4*)(H + (wm + i * 16 + lm) * 136 + wn + j * 16 + lk * 4) = o;
      }
    __syncthreads();
    for (int i = tid; i < 128 * 16; i += 256) {
      int row = i >> 4, c8 = i & 15;
      int gm = m0 + row, gn = n0 + c8 * 8;
      if (gm < M && gn < ncol)
        *(f16x8*)(C + (size_t)gm * ncol + gn) = *(const f16x8*)(H + row * 136 + c8 * 8);
    }
    __syncthreads();
  }
}

// ---------------- vectorized edge aggregation for one column pass ----------------
template <int PW>
__global__ __launch_bounds__(256) void k_edge_v(
    const f16* __restrict__ Y, const int* __restrict__ sps,
    const int* __restrict__ off, const float* __restrict__ sinvp,
    const float* __restrict__ bias, f16* __restrict__ hout,
    const int* __restrict__ mark, int N, int pass) {
  constexpr int CPL = PW / 16;
  constexpr int LDY = 9 * PW;
  int t = threadIdx.x;
  int g = t >> 4, st = t & 15;
  int n = blockIdx.x * 16 + g;
  if (n >= N) return;
  if (mark && !mark[n]) return;
  float sv = (st < 8) ? sinvp[n * 8 + st] : 0.f;
  int e0 = off[n], e1 = off[n + 1];
  float a[CPL], b2[CPL];
  {
    const f16* rp = Y + (size_t)n * LDY + 8 * PW + st * CPL;
    const float* bp = bias + pass * PW + st * CPL;
#pragma unroll
    for (int q = 0; q < CPL; q++) { a[q] = (float)rp[q] + bp[q]; b2[q] = 0.f; }
  }
  int sgbase = t & 48;
  int e = e0;
  for (; e + 1 < e1; e += 2) {
    int p0 = sps[e], p1 = sps[e + 1];
    int s0 = p0 & 0xFFFFF, ty0 = ((unsigned)p0) >> 20;
    int s1 = p1 & 0xFFFFF, ty1 = ((unsigned)p1) >> 20;
    float sc0 = __shfl(sv, sgbase | ty0);
    float sc1 = __shfl(sv, sgbase | ty1);
    const f16* q0 = Y + (size_t)s0 * LDY + ty0 * PW + st * CPL;
    const f16* q1 = Y + (size_t)s1 * LDY + ty1 * PW + st * CPL;
    if constexpr (PW == 64) {
      f16x4 v0 = *(const f16x4*)q0;
      f16x4 v1 = *(const f16x4*)q1;
      a[0] += (float)v0[0] * sc0; a[1] += (float)v0[1] * sc0;
      a[2] += (float)v0[2] * sc0; a[3] += (float)v0[3] * sc0;
      b2[0] += (float)v1[0] * sc1; b2[1] += (float)v1[1] * sc1;
      b2[2] += (float)v1[2] * sc1; b2[3] += (float)v1[3] * sc1;
    } else {
      f16x2 v0 = *(const f16x2*)q0;
      f16x2 v1 = *(const f16x2*)q1;
      a[0] += (float)v0[0] * sc0; a[1] += (float)v0[1] * sc0;
      b2[0] += (float)v1[0] * sc1; b2[1] += (float)v1[1] * sc1;
    }
  }
  if (e < e1) {
    int p0 = sps[e];
    int s0 = p0 & 0xFFFFF, ty0 = ((unsigned)p0) >> 20;
    float sc0 = __shfl(sv, sgbase | ty0);
    const f16* q0 = Y + (size_t)s0 * LDY + ty0 * PW + st * CPL;
    if constexpr (PW == 64) {
      f16x4 v0 = *(const f16x4*)q0;
      a[0] += (float)v0[0] * sc0; a[1] += (float)v0[1] * sc0;
      a[2] += (float)v0[2] * sc0; a[3] += (float)v0[3] * sc0;
    } else {
      f16x2 v0 = *(const f16x2*)q0;
      a[0] += (float)v0[0] * sc0; a[1] += (float)v0[1] * sc0;
    }
  }
  if constexpr (PW == 64) {
    f16x4 o;
#pragma unroll
    for (int q = 0; q < 4; q++) o[q] = (f16)fmaxf(a[q] + b2[q], 0.f);
    *(f16x4*)(hout + (size_t)n * 128 + pass * PW + st * 4) = o;
  } else {
    f16x2 o;
#pragma unroll
    for (int q = 0; q < 2; q++) o[q] = (f16)fmaxf(a[q] + b2[q], 0.f);
    *(f16x2*)(hout + (size_t)n * 128 + pass * PW + st * 2) = o;
  }
}

// ---------------- layer 3: only at root rows, weights in LDS ----------------
__global__ __launch_bounds__(128) void k_layer3(const f16* __restrict__ h2,
                                                const int* __restrict__ sps,
                                                const int* __restrict__ off,
                                                const float* __restrict__ sinvp,
                                                const int* __restrict__ ridx,
                                                const float* __restrict__ wrel,
                                                const float* __restrict__ wroot,
                                                const float* __restrict__ b3,
                                                float* __restrict__ out) {
  __shared__ f16 W[9 * 2048];
  __shared__ float red[2][16];
  __shared__ float sinv_s[8];
  int t = threadIdx.x;
  int n = ridx[blockIdx.x];
  for (int j = t; j < 9 * 2048; j += 128)
    W[j] = (f16)((j < 8 * 2048) ? wrel[j] : wroot[j - 8 * 2048]);
  if (t < 8) sinv_s[t] = sinvp[n * 8 + t];
  __syncthreads();
  int e0 = off[n], e1 = off[n + 1];
  int c = t & 15, kg = t >> 4;
  float a = 0.f;
  for (int e = e0; e < e1; e++) {
    int ps = sps[e];
    int s = ps & 0xFFFFF, ty = ((unsigned)ps) >> 20;
    float p = 0.f;
#pragma unroll
    for (int j = 0; j < 16; j++) {
      int k = kg * 16 + j;
      p += (float)h2[(size_t)s * 128 + k] * (float)W[ty * 2048 + k * 16 + c];
    }
    a += sinv_s[ty] * p;
  }
  {
    float p = 0.f;
#pragma unroll
    for (int j = 0; j < 16; j++) {
      int k = kg * 16 + j;
      p += (float)h2[(size_t)n * 128 + k] * (float)W[8 * 2048 + k * 16 + c];
    }
    a += p;
  }
  a += __shfl_xor(a, 16);
  a += __shfl_xor(a, 32);
  if ((t & 63) < 16) red[t >> 6][t & 15] = a;
  __syncthreads();
  if (t < 16) out[(size_t)blockIdx.x * 16 + t] = red[0][t] + red[1][t] + b3[t];
}

// ---------------- host ----------------
extern "C" void kernel_launch(void* const* d_in, const int* in_sizes, int n_in,
                              void* d_out, int out_size, void* d_ws, size_t ws_size,
                              hipStream_t stream) {
  const float* x     = (const float*)d_in[0];
  const int*   eidx  = (const int*)d_in[1];
  const int*   etyp  = (const int*)d_in[2];
  const int*   ridx  = (const int*)d_in[3];
  const float* wrel1 = (const float*)d_in[4];
  const float* root1 = (const float*)d_in[5];
  const float* b1    = (const float*)d_in[6];
  const float* wrel2 = (const float*)d_in[7];
  const float* root2 = (const float*)d_in[8];
  const float* b2    = (const float*)d_in[9];
  const float* wrel3 = (const float*)d_in[10];
  const float* root3 = (const float*)d_in[11];
  const float* b3    = (const float*)d_in[12];

  int N = in_sizes[0] / 128;
  int E = in_sizes[2];
  int NROOT = in_sizes[3];
  const int* esrc = eidx;
  const int* edst = eidx + E;

  char* p = (char*)d_ws;
  auto alloc = [&](size_t bytes) { void* r = (void*)p; p += (bytes + 255) & ~(size_t)255; return r; };
  int*   off   = (int*)alloc((size_t)(N + 1) * 4);
  int*   sps   = (int*)alloc((size_t)E * 4);
  f16*   h1    = (f16*)alloc((size_t)N * 128 * 2);
  f16*   h2    = (f16*)alloc((size_t)N * 128 * 2);   // also holds f16(x) for layer 1
  int*   mark  = (int*)alloc((size_t)N * 4);
  float* sinvp = (float*)alloc((size_t)N * 8 * 4);
  f16*   Wt    = (f16*)alloc((size_t)640 * 128 * 2);
  int*   bcnt  = (int*)alloc(512 * 4);
  int*   boff  = (int*)alloc(513 * 4);
  int*   bfill = (int*)alloc(512 * 4);

  size_t used = (size_t)(p - (char*)d_ws);
  size_t remain = ws_size > used ? ws_size - used : 0;
  int PW = (remain >= (size_t)N * 9 * 64 * 2 + (1u << 20)) ? 64 : 32;
  int ldy = 9 * PW;
  f16* Y = (f16*)alloc((size_t)N * ldy * 2);
  // setup-only scratch lives in Y's region (dead until first GEMM writes Y):
  int* tmp  = (int*)Y;             // E ints (phase-A bucket-grouped edges)
  int* part = tmp + E;             // 4096 ints (fallback scan partials)
  int* fill = part + 4096;         // N ints (fallback scatter only)

  int nbuck = (N + 255) >> 8;
  int nbA = (E + ACHUNK - 1) / ACHUNK;
  hipMemsetAsync(mark, 0, (size_t)N * 4, stream);

  if (nbuck <= 512) {
    hipMemsetAsync(bcnt, 0, 512 * 4, stream);
    hipMemsetAsync(bfill, 0, 512 * 4, stream);
    k_bhist<<<nbA, 256, 0, stream>>>(edst, E, bcnt, nbuck);
    k_bscan<<<1, 512, 0, stream>>>(bcnt, boff, nbuck);
    k_bucketA<<<nbA, 256, 0, stream>>>(esrc, edst, etyp, E, boff, bfill, tmp, nbuck);
    k_bucketB2<<<nbuck, 256, 0, stream>>>(tmp, boff, off, sps, N);
    k_sentinel<<<1, 1, 0, stream>>>(off + N, E);
  } else {
    int eb = (E + 255) / 256;
    hipMemsetAsync(off, 0, (size_t)(N + 1) * 4, stream);
    hipMemsetAsync(fill, 0, (size_t)N * 4, stream);
    k_hist<<<eb, 256, 0, stream>>>(edst, E, off);
    int nb1 = (N + 4095) / 4096;
    k_scan1<<<nb1, 256, 0, stream>>>(off, off, part, N);
    k_scan2<<<1, 256, 0, stream>>>(part, nb1);
    k_scan3<<<(N + 255) / 256, 256, 0, stream>>>(off, part, N);
    k_sentinel<<<1, 1, 0, stream>>>(off + N, E);
    k_scatter<<<eb, 256, 0, stream>>>(esrc, edst, etyp, E, off, fill, sps);
  }
  k_mark<<<NROOT, 64, 0, stream>>>(ridx, off, sps, mark);
  int ng16 = (N + 15) / 16;
  k_sinvp<<<ng16, 256, 0, stream>>>(sps, off, sinvp, N);
  k_f32_to_f16<<<((N * 32) + 255) / 256, 256, 0, stream>>>(x, h2, N * 32);

  int mb = (N + 127) / 128;
  int NT = (ldy + 127) / 128;
  int npass = 128 / PW;

  // layer 1: A = f16(x) (aliased in h2)
  for (int ps = 0; ps < npass; ps++) {
    k_tpw<<<NT * 128, 128, 0, stream>>>(wrel1, root1, Wt, PW, ps);
    k_gemm3<<<mb, 256, 0, stream>>>(h2, Wt, Y, N, ldy);
    if (PW == 64)
      k_edge_v<64><<<ng16, 256, 0, stream>>>(Y, sps, off, sinvp, b1, h1, nullptr, N, ps);
    else
      k_edge_v<32><<<ng16, 256, 0, stream>>>(Y, sps, off, sinvp, b1, h1, nullptr, N, ps);
  }
  // layer 2: A = h1, edge pass pruned to marked nodes
  for (int ps = 0; ps < npass; ps++) {
    k_tpw<<<NT * 128, 128, 0, stream>>>(wrel2, root2, Wt, PW, ps);
    k_gemm3<<<mb, 256, 0, stream>>>(h1, Wt, Y, N, ldy);
    if (PW == 64)
      k_edge_v<64><<<ng16, 256, 0, stream>>>(Y, sps, off, sinvp, b2, h2, mark, N, ps);
    else
      k_edge_v<32><<<ng16, 256, 0, stream>>>(Y, sps, off, sinvp, b2, h2, mark, N, ps);
  }
  k_layer3<<<NROOT, 128, 0, stream>>>(h2, sps, off, sinvp, ridx, wrel3, root3, b3,
                                      (float*)d_out);
}

// Round 12
// 492.506 us; speedup vs baseline: 1.0833x; 1.0039x over previous
//
#include <hip/hip_runtime.h>
#include <hip/hip_fp16.h>

// RGCN 3-layer, transform-first with column-split passes:
//   Y = A @ [W_0..W_7, W_root] restricted to output cols [p*PW,(p+1)*PW)
//   h[n, cols] = relu( Y[n,rootblk] + sum_e (1/cnt[n,ty]) * Y[src_e, ty-blk] + bias )
// Edge sort: bucket pipeline (bucket = 256 dst nodes). sinvp precomputed.
// Edge pass: 16-lane subgroups, f16x4 vector gather, shfl sinv broadcast.
// GEMM (k_gemm3): grid (m-tiles, 2); A staged once -> registers; each block
// covers col-tiles blockIdx.y, +2, ... (2x occupancy vs 1-block-per-m-tile);
// swapped MFMA (mfma(b,a)) -> f16x4 LDS repack -> coalesced f16x8 stores.
// Layer-2 pruned to marked nodes; layer 3 at roots only.

typedef _Float16 f16;
typedef _Float16 f16x2 __attribute__((ext_vector_type(2)));
typedef _Float16 f16x4 __attribute__((ext_vector_type(4)));
typedef _Float16 f16x8 __attribute__((ext_vector_type(8)));
typedef float f32x4 __attribute__((ext_vector_type(4)));

#define NREL 8
#define ACHUNK 8192

// ---------------- fallback setup kernels (N > 131072 only) ----------------
__global__ void k_hist(const int* __restrict__ dst, int E, int* __restrict__ cnt) {
  int e = blockIdx.x * 256 + threadIdx.x;
  if (e < E) atomicAdd(&cnt[dst[e]], 1);
}

__global__ void k_scan1(const int* __restrict__ in, int* __restrict__ out,
                        int* __restrict__ part, int n) {
  __shared__ int sh[256];
  int b = blockIdx.x, t = threadIdx.x;
  int base = b * 4096 + t * 16;
  int v[16]; int s = 0;
#pragma unroll
  for (int j = 0; j < 16; j++) { int idx = base + j; int x = (idx < n) ? in[idx] : 0; v[j] = s; s += x; }
  sh[t] = s; __syncthreads();
  for (int off = 1; off < 256; off <<= 1) {
    int x = 0; if (t >= off) x = sh[t - off];
    __syncthreads();
    if (t >= off) sh[t] += x;
    __syncthreads();
  }
  int excl = (t == 0) ? 0 : sh[t - 1];
  if (t == 255) part[b] = sh[255];
#pragma unroll
  for (int j = 0; j < 16; j++) { int idx = base + j; if (idx < n) out[idx] = v[j] + excl; }
}

__global__ void k_scan2(int* __restrict__ part, int nb) {
  __shared__ int sh[256];
  int t = threadIdx.x;
  sh[t] = (t < nb) ? part[t] : 0; __syncthreads();
  for (int off = 1; off < 256; off <<= 1) {
    int x = 0; if (t >= off) x = sh[t - off];
    __syncthreads();
    if (t >= off) sh[t] += x;
    __syncthreads();
  }
  if (t < nb) part[t] = (t == 0) ? 0 : sh[t - 1];
}

__global__ void k_scan3(int* __restrict__ out, const int* __restrict__ part, int n) {
  int i = blockIdx.x * 256 + threadIdx.x;
  if (i < n) out[i] += part[i >> 12];
}

__global__ void k_scatter(const int* __restrict__ src, const int* __restrict__ dstv,
                          const int* __restrict__ et, int E,
                          const int* __restrict__ off, int* __restrict__ fill,
                          int* __restrict__ sps) {
  int e = blockIdx.x * 256 + threadIdx.x;
  if (e >= E) return;
  int d = dstv[e];
  int pos = off[d] + atomicAdd(&fill[d], 1);
  sps[pos] = src[e] | (et[e] << 20);
}

__global__ void k_sentinel(int* __restrict__ p, int v) { *p = v; }

// ---------------- bucket pipeline (bucket = 256 consecutive dst nodes) ----------
__global__ __launch_bounds__(256) void k_bhist(const int* __restrict__ dstv, int E,
                                               int* __restrict__ bcnt, int nbuck) {
  __shared__ int h[512];
  int t = threadIdx.x;
  for (int i = t; i < 512; i += 256) h[i] = 0;
  __syncthreads();
  int lo = blockIdx.x * ACHUNK;
  int hi = lo + ACHUNK < E ? lo + ACHUNK : E;
  for (int e = lo + t; e < hi; e += 256) atomicAdd(&h[dstv[e] >> 8], 1);
  __syncthreads();
  for (int i = t; i < nbuck; i += 256)
    if (h[i]) atomicAdd(&bcnt[i], h[i]);
}

__global__ __launch_bounds__(512) void k_bscan(const int* __restrict__ bcnt,
                                               int* __restrict__ boff, int nbuck) {
  __shared__ int sh[512];
  int t = threadIdx.x;
  sh[t] = (t < nbuck) ? bcnt[t] : 0;
  __syncthreads();
  for (int o = 1; o < 512; o <<= 1) {
    int v = 0; if (t >= o) v = sh[t - o];
    __syncthreads();
    sh[t] += v;
    __syncthreads();
  }
  if (t <= nbuck && t < 512) boff[t] = (t == 0) ? 0 : sh[t - 1];
  if (t == 511 && nbuck >= 512) boff[nbuck] = sh[511];
}

__global__ __launch_bounds__(256) void k_bucketA(
    const int* __restrict__ src, const int* __restrict__ dstv,
    const int* __restrict__ et, int E, const int* __restrict__ boff,
    int* __restrict__ bfill, int* __restrict__ tmp, int nbuck) {
  __shared__ int hist[512];
  __shared__ int base[512];
  int t = threadIdx.x;
  int lo = blockIdx.x * ACHUNK;
  int hi = lo + ACHUNK < E ? lo + ACHUNK : E;
  for (int i = t; i < nbuck; i += 256) hist[i] = 0;
  __syncthreads();
  for (int e = lo + t; e < hi; e += 256)
    atomicAdd(&hist[dstv[e] >> 8], 1);
  __syncthreads();
  for (int i = t; i < nbuck; i += 256) {
    int c = hist[i];
    base[i] = c ? (boff[i] + atomicAdd(&bfill[i], c)) : 0;
  }
  __syncthreads();
  for (int e = lo + t; e < hi; e += 256) {
    int d = dstv[e];
    int b = d >> 8;
    int pos = atomicAdd(&base[b], 1);
    tmp[pos] = src[e] | (et[e] << 20) | ((d & 255) << 23);
  }
}

__global__ __launch_bounds__(256) void k_bucketB2(const int* __restrict__ tmp,
                                                  const int* __restrict__ boff,
                                                  int* __restrict__ off,
                                                  int* __restrict__ sps, int N) {
  __shared__ int cnt[256];
  __shared__ int sh[256];
  __shared__ int loff[257];
  int b = blockIdx.x, t = threadIdx.x;
  int n0 = b << 8;
  int nn = (N - n0) < 256 ? (N - n0) : 256;
  cnt[t] = 0;
  __syncthreads();
  int e0 = boff[b], e1 = boff[b + 1];
  for (int e = e0 + t; e < e1; e += 256)
    atomicAdd(&cnt[(tmp[e] >> 23) & 255], 1);
  __syncthreads();
  sh[t] = cnt[t];
  __syncthreads();
  for (int o = 1; o < 256; o <<= 1) {
    int v = 0; if (t >= o) v = sh[t - o];
    __syncthreads();
    sh[t] += v;
    __syncthreads();
  }
  loff[t] = (t == 0) ? 0 : sh[t - 1];
  if (t == 255) loff[256] = sh[255];
  __syncthreads();
  if (t < nn) off[n0 + t] = e0 + loff[t];
  cnt[t] = 0;   // reuse as fill
  __syncthreads();
  for (int e = e0 + t; e < e1; e += 256) {
    int v = tmp[e];
    int dl = (v >> 23) & 255;
    int pos = e0 + loff[dl] + atomicAdd(&cnt[dl], 1);
    sps[pos] = v & 0x7FFFFF;
  }
}

// mark nodes whose h2 is read by layer 3: roots + src of root in-edges
__global__ void k_mark(const int* __restrict__ ridx, const int* __restrict__ off,
                       const int* __restrict__ sps, int* __restrict__ mark) {
  int i = blockIdx.x, t = threadIdx.x;
  int n = ridx[i];
  if (t == 0) mark[n] = 1;
  int e0 = off[n], e1 = off[n + 1];
  for (int e = e0 + t; e < e1; e += 64) mark[sps[e] & 0xFFFFF] = 1;
}

// precompute per-(node,type) inverse counts
__global__ __launch_bounds__(256) void k_sinvp(const int* __restrict__ sps,
                                               const int* __restrict__ off,
                                               float* __restrict__ sinvp, int N) {
  __shared__ int c[16][8];
  int t = threadIdx.x;
  int g = t >> 4, st = t & 15;
  int n = blockIdx.x * 16 + g;
  if (st < 8) c[g][st] = 0;
  __syncthreads();
  if (n < N) {
    int e0 = off[n], e1 = off[n + 1];
    for (int e = e0 + st; e < e1; e += 16)
      atomicAdd(&c[g][((unsigned)sps[e]) >> 20], 1);
  }
  __syncthreads();
  if (n < N && st < 8) {
    int cc = c[g][st];
    sinvp[n * 8 + st] = 1.0f / (float)(cc > 1 ? cc : 1);
  }
}

__global__ void k_f32_to_f16(const float* __restrict__ in, f16* __restrict__ out, int n4) {
  int i = blockIdx.x * 256 + threadIdx.x;
  if (i < n4) {
    float4 v = ((const float4*)in)[i];
    f16x4 o; o[0] = (f16)v.x; o[1] = (f16)v.y; o[2] = (f16)v.z; o[3] = (f16)v.w;
    ((f16x4*)out)[i] = o;
  }
}

// weights for pass p: Wt[row][k], row = cb*PW + j -> source col p*PW+j of chunk cb
__global__ void k_tpw(const float* __restrict__ wrel, const float* __restrict__ wroot,
                      f16* __restrict__ dst, int PW, int p) {
  int row = blockIdx.x, k = threadIdx.x;
  float v = 0.f;
  if (row < 9 * PW) {
    int cb = row / PW, j = row - cb * PW;
    int col = p * PW + j;
    v = (cb < 8) ? wrel[(size_t)cb * 16384 + k * 128 + col] : wroot[k * 128 + col];
  }
  dst[(size_t)row * 128 + k] = (f16)v;
}

// ---------------- GEMM: C[M x ncol] = A[M x 128] * Bt^T ----------------
// grid (mb, 2): block handles col-tiles blockIdx.y, +gridDim.y, ...
// A staged once -> 16 reg fragments; As reused as repack buffer H. Swapped
// MFMA: lane owns (row=lm, 4 consecutive cols) -> f16x4 LDS repack ->
// coalesced f16x8 global stores.
__global__ __launch_bounds__(256) void k_gemm3(const f16* __restrict__ A,
                                               const f16* __restrict__ Bt,
                                               f16* __restrict__ C, int M, int ncol) {
  __shared__ f16 As[128 * 136];
  int tid = threadIdx.x;
  int m0 = blockIdx.x * 128;
#pragma unroll
  for (int cch = 0; cch < 8; cch++) {
    int ci = tid + cch * 256;
    int row = ci >> 4, c8 = ci & 15;
    int gm = m0 + row;
    f16x8 va = {};
    if (gm < M) va = *(const f16x8*)(A + (size_t)gm * 128 + c8 * 8);
    *(f16x8*)(As + row * 136 + c8 * 8) = va;
  }
  __syncthreads();
  int wid = tid >> 6, lane = tid & 63;
  int wm = (wid & 1) * 64, wn = (wid >> 1) * 64;
  int lm = lane & 15, lk = lane >> 4;
  // A fragments to registers (4 ks x 4 i); As is then dead -> reuse as H
  f16x8 af[4][4];
#pragma unroll
  for (int ks = 0; ks < 4; ks++)
#pragma unroll
    for (int i = 0; i < 4; i++)
      af[ks][i] = *(const f16x8*)(As + (wm + i * 16 + lm) * 136 + ks * 32 + lk * 8);
  __syncthreads();
  f16* H = As;
  int NT = (ncol + 127) >> 7;
  for (int nt = blockIdx.y; nt < NT; nt += gridDim.y) {
    int n0 = nt * 128;
    f32x4 acc[4][4] = {};
#pragma unroll
    for (int ks = 0; ks < 4; ks++) {
      f16x8 b[4];
#pragma unroll
      for (int j = 0; j < 4; j++)
        b[j] = *(const f16x8*)(Bt + (size_t)(n0 + wn + j * 16 + lm) * 128 + ks * 32 + lk * 8);
#pragma unroll
      for (int i = 0; i < 4; i++)
#pragma unroll
        for (int j = 0; j < 4; j++)
          acc[i][j] = __builtin_amdgcn_mfma_f32_16x16x32_f16(b[j], af[ks][i], acc[i][j], 0, 0, 0);
    }
    // repack: lane owns row (wm+i*16+lm), cols (wn+j*16+lk*4 .. +3)
#pragma unroll
    for (int i = 0; i < 4; i++)
#pragma unroll
      for (int j = 0; j < 4; j++) {
        f16x4 o;
        o[0] = (f16)acc[i][j][0]; o[1] = (f16)acc[i][j][1];
        o[2] = (f16)acc[i][j][2]; o[3] = (f16)acc[i][j][3];
        *(f16x4*)(H + (wm + i * 16 + lm) * 136 + wn + j * 16 + lk * 4) = o;
      }
    __syncthreads();
    for (int i = tid; i < 128 * 16; i += 256) {
      int row = i >> 4, c8 = i & 15;
      int gm = m0 + row, gn = n0 + c8 * 8;
      if (gm < M && gn < ncol)
        *(f16x8*)(C + (size_t)gm * ncol + gn) = *(const f16x8*)(H + row * 136 + c8 * 8);
    }
    __syncthreads();
  }
}

// ---------------- vectorized edge aggregation for one column pass ----------------
template <int PW>
__global__ __launch_bounds__(256) void k_edge_v(
    const f16* __restrict__ Y, const int* __restrict__ sps,
    const int* __restrict__ off, const float* __restrict__ sinvp,
    const float* __restrict__ bias, f16* __restrict__ hout,
    const int* __restrict__ mark, int N, int pass) {
  constexpr int CPL = PW / 16;
  constexpr int LDY = 9 * PW;
  int t = threadIdx.x;
  int g = t >> 4, st = t & 15;
  int n = blockIdx.x * 16 + g;
  if (n >= N) return;
  if (mark && !mark[n]) return;
  float sv = (st < 8) ? sinvp[n * 8 + st] : 0.f;
  int e0 = off[n], e1 = off[n + 1];
  float a[CPL], b2[CPL];
  {
    const f16* rp = Y + (size_t)n * LDY + 8 * PW + st * CPL;
    const float* bp = bias + pass * PW + st * CPL;
#pragma unroll
    for (int q = 0; q < CPL; q++) { a[q] = (float)rp[q] + bp[q]; b2[q] = 0.f; }
  }
  int sgbase = t & 48;
  int e = e0;
  for (; e + 1 < e1; e += 2) {
    int p0 = sps[e], p1 = sps[e + 1];
    int s0 = p0 & 0xFFFFF, ty0 = ((unsigned)p0) >> 20;
    int s1 = p1 & 0xFFFFF, ty1 = ((unsigned)p1) >> 20;
    float sc0 = __shfl(sv, sgbase | ty0);
    float sc1 = __shfl(sv, sgbase | ty1);
    const f16* q0 = Y + (size_t)s0 * LDY + ty0 * PW + st * CPL;
    const f16* q1 = Y + (size_t)s1 * LDY + ty1 * PW + st * CPL;
    if constexpr (PW == 64) {
      f16x4 v0 = *(const f16x4*)q0;
      f16x4 v1 = *(const f16x4*)q1;
      a[0] += (float)v0[0] * sc0; a[1] += (float)v0[1] * sc0;
      a[2] += (float)v0[2] * sc0; a[3] += (float)v0[3] * sc0;
      b2[0] += (float)v1[0] * sc1; b2[1] += (float)v1[1] * sc1;
      b2[2] += (float)v1[2] * sc1; b2[3] += (float)v1[3] * sc1;
    } else {
      f16x2 v0 = *(const f16x2*)q0;
      f16x2 v1 = *(const f16x2*)q1;
      a[0] += (float)v0[0] * sc0; a[1] += (float)v0[1] * sc0;
      b2[0] += (float)v1[0] * sc1; b2[1] += (float)v1[1] * sc1;
    }
  }
  if (e < e1) {
    int p0 = sps[e];
    int s0 = p0 & 0xFFFFF, ty0 = ((unsigned)p0) >> 20;
    float sc0 = __shfl(sv, sgbase | ty0);
    const f16* q0 = Y + (size_t)s0 * LDY + ty0 * PW + st * CPL;
    if constexpr (PW == 64) {
      f16x4 v0 = *(const f16x4*)q0;
      a[0] += (float)v0[0] * sc0; a[1] += (float)v0[1] * sc0;
      a[2] += (float)v0[2] * sc0; a[3] += (float)v0[3] * sc0;
    } else {
      f16x2 v0 = *(const f16x2*)q0;
      a[0] += (float)v0[0] * sc0; a[1] += (float)v0[1] * sc0;
    }
  }
  if constexpr (PW == 64) {
    f16x4 o;
#pragma unroll
    for (int q = 0; q < 4; q++) o[q] = (f16)fmaxf(a[q] + b2[q], 0.f);
    *(f16x4*)(hout + (size_t)n * 128 + pass * PW + st * 4) = o;
  } else {
    f16x2 o;
#pragma unroll
    for (int q = 0; q < 2; q++) o[q] = (f16)fmaxf(a[q] + b2[q], 0.f);
    *(f16x2*)(hout + (size_t)n * 128 + pass * PW + st * 2) = o;
  }
}

// ---------------- layer 3: only at root rows, weights in LDS ----------------
__global__ __launch_bounds__(128) void k_layer3(const f16* __restrict__ h2,
                                                const int* __restrict__ sps,
                                                const int* __restrict__ off,
                                                const float* __restrict__ sinvp,
                                                const int* __restrict__ ridx,
                                                const float* __restrict__ wrel,
                                                const float* __restrict__ wroot,
                                                const float* __restrict__ b3,
                                                float* __restrict__ out) {
  __shared__ f16 W[9 * 2048];
  __shared__ float red[2][16];
  __shared__ float sinv_s[8];
  int t = threadIdx.x;
  int n = ridx[blockIdx.x];
  for (int j = t; j < 9 * 2048; j += 128)
    W[j] = (f16)((j < 8 * 2048) ? wrel[j] : wroot[j - 8 * 2048]);
  if (t < 8) sinv_s[t] = sinvp[n * 8 + t];
  __syncthreads();
  int e0 = off[n], e1 = off[n + 1];
  int c = t & 15, kg = t >> 4;
  float a = 0.f;
  for (int e = e0; e < e1; e++) {
    int ps = sps[e];
    int s = ps & 0xFFFFF, ty = ((unsigned)ps) >> 20;
    float p = 0.f;
#pragma unroll
    for (int j = 0; j < 16; j++) {
      int k = kg * 16 + j;
      p += (float)h2[(size_t)s * 128 + k] * (float)W[ty * 2048 + k * 16 + c];
    }
    a += sinv_s[ty] * p;
  }
  {
    float p = 0.f;
#pragma unroll
    for (int j = 0; j < 16; j++) {
      int k = kg * 16 + j;
      p += (float)h2[(size_t)n * 128 + k] * (float)W[8 * 2048 + k * 16 + c];
    }
    a += p;
  }
  a += __shfl_xor(a, 16);
  a += __shfl_xor(a, 32);
  if ((t & 63) < 16) red[t >> 6][t & 15] = a;
  __syncthreads();
  if (t < 16) out[(size_t)blockIdx.x * 16 + t] = red[0][t] + red[1][t] + b3[t];
}

// ---------------- host ----------------
extern "C" void kernel_launch(void* const* d_in, const int* in_sizes, int n_in,
                              void* d_out, int out_size, void* d_ws, size_t ws_size,
                              hipStream_t stream) {
  const float* x     = (const float*)d_in[0];
  const int*   eidx  = (const int*)d_in[1];
  const int*   etyp  = (const int*)d_in[2];
  const int*   ridx  = (const int*)d_in[3];
  const float* wrel1 = (const float*)d_in[4];
  const float* root1 = (const float*)d_in[5];
  const float* b1    = (const float*)d_in[6];
  const float* wrel2 = (const float*)d_in[7];
  const float* root2 = (const float*)d_in[8];
  const float* b2    = (const float*)d_in[9];
  const float* wrel3 = (const float*)d_in[10];
  const float* root3 = (const float*)d_in[11];
  const float* b3    = (const float*)d_in[12];

  int N = in_sizes[0] / 128;
  int E = in_sizes[2];
  int NROOT = in_sizes[3];
  const int* esrc = eidx;
  const int* edst = eidx + E;

  char* p = (char*)d_ws;
  auto alloc = [&](size_t bytes) { void* r = (void*)p; p += (bytes + 255) & ~(size_t)255; return r; };
  int*   off   = (int*)alloc((size_t)(N + 1) * 4);
  int*   sps   = (int*)alloc((size_t)E * 4);
  f16*   h1    = (f16*)alloc((size_t)N * 128 * 2);
  f16*   h2    = (f16*)alloc((size_t)N * 128 * 2);   // also holds f16(x) for layer 1
  int*   mark  = (int*)alloc((size_t)N * 4);
  float* sinvp = (float*)alloc((size_t)N * 8 * 4);
  f16*   Wt    = (f16*)alloc((size_t)640 * 128 * 2);
  int*   bcnt  = (int*)alloc(512 * 4);
  int*   boff  = (int*)alloc(513 * 4);
  int*   bfill = (int*)alloc(512 * 4);

  size_t used = (size_t)(p - (char*)d_ws);
  size_t remain = ws_size > used ? ws_size - used : 0;
  int PW = (remain >= (size_t)N * 9 * 64 * 2 + (1u << 20)) ? 64 : 32;
  int ldy = 9 * PW;
  f16* Y = (f16*)alloc((size_t)N * ldy * 2);
  // setup-only scratch lives in Y's region (dead until first GEMM writes Y):
  int* tmp  = (int*)Y;             // E ints (phase-A bucket-grouped edges)
  int* part = tmp + E;             // 4096 ints (fallback scan partials)
  int* fill = part + 4096;         // N ints (fallback scatter only)

  int nbuck = (N + 255) >> 8;
  int nbA = (E + ACHUNK - 1) / ACHUNK;
  hipMemsetAsync(mark, 0, (size_t)N * 4, stream);

  if (nbuck <= 512) {
    hipMemsetAsync(bcnt, 0, 512 * 4, stream);
    hipMemsetAsync(bfill, 0, 512 * 4, stream);
    k_bhist<<<nbA, 256, 0, stream>>>(edst, E, bcnt, nbuck);
    k_bscan<<<1, 512, 0, stream>>>(bcnt, boff, nbuck);
    k_bucketA<<<nbA, 256, 0, stream>>>(esrc, edst, etyp, E, boff, bfill, tmp, nbuck);
    k_bucketB2<<<nbuck, 256, 0, stream>>>(tmp, boff, off, sps, N);
    k_sentinel<<<1, 1, 0, stream>>>(off + N, E);
  } else {
    int eb = (E + 255) / 256;
    hipMemsetAsync(off, 0, (size_t)(N + 1) * 4, stream);
    hipMemsetAsync(fill, 0, (size_t)N * 4, stream);
    k_hist<<<eb, 256, 0, stream>>>(edst, E, off);
    int nb1 = (N + 4095) / 4096;
    k_scan1<<<nb1, 256, 0, stream>>>(off, off, part, N);
    k_scan2<<<1, 256, 0, stream>>>(part, nb1);
    k_scan3<<<(N + 255) / 256, 256, 0, stream>>>(off, part, N);
    k_sentinel<<<1, 1, 0, stream>>>(off + N, E);
    k_scatter<<<eb, 256, 0, stream>>>(esrc, edst, etyp, E, off, fill, sps);
  }
  k_mark<<<NROOT, 64, 0, stream>>>(ridx, off, sps, mark);
  int ng16 = (N + 15) / 16;
  k_sinvp<<<ng16, 256, 0, stream>>>(sps, off, sinvp, N);
  k_f32_to_f16<<<((N * 32) + 255) / 256, 256, 0, stream>>>(x, h2, N * 32);

  int mb = (N + 127) / 128;
  int NT = (ldy + 127) / 128;
  int npass = 128 / PW;

  // layer 1: A = f16(x) (aliased in h2)
  for (int ps = 0; ps < npass; ps++) {
    k_tpw<<<NT * 128, 128, 0, stream>>>(wrel1, root1, Wt, PW, ps);
    k_gemm3<<<dim3(mb, 2), 256, 0, stream>>>(h2, Wt, Y, N, ldy);
    if (PW == 64)
      k_edge_v<64><<<ng16, 256, 0, stream>>>(Y, sps, off, sinvp, b1, h1, nullptr, N, ps);
    else
      k_edge_v<32><<<ng16, 256, 0, stream>>>(Y, sps, off, sinvp, b1, h1, nullptr, N, ps);
  }
  // layer 2: A = h1, edge pass pruned to marked nodes
  for (int ps = 0; ps < npass; ps++) {
    k_tpw<<<NT * 128, 128, 0, stream>>>(wrel2, root2, Wt, PW, ps);
    k_gemm3<<<dim3(mb, 2), 256, 0, stream>>>(h1, Wt, Y, N, ldy);
    if (PW == 64)
      k_edge_v<64><<<ng16, 256, 0, stream>>>(Y, sps, off, sinvp, b2, h2, mark, N, ps);
    else
      k_edge_v<32><<<ng16, 256, 0, stream>>>(Y, sps, off, sinvp, b2, h2, mark, N, ps);
  }
  k_layer3<<<NROOT, 128, 0, stream>>>(h2, sps, off, sinvp, ridx, wrel3, root3, b3,
                                      (float*)d_out);
}